// Round 4
// baseline (1088.288 us; speedup 1.0000x reference)
//
#include <hip/hip_runtime.h>
#include <hip/hip_bf16.h>
#include <cstdint>

// ---------------------------------------------------------------------------
// MolGraphEncoder r4: fused per-layer kernel = CSR aggregation (wave/row,
// fp32 accum) -> bf16 LDS tile (XOR-swizzled) -> MFMA GEMM + epilogue.
// Eliminates the aggbuf HBM round-trip of r3.
// ---------------------------------------------------------------------------

typedef __attribute__((ext_vector_type(8))) short short8;
typedef __attribute__((ext_vector_type(4))) float f32x4;

__device__ __forceinline__ float b2f(unsigned int hi16) {
    return __builtin_bit_cast(float, hi16);
}
__device__ __forceinline__ unsigned short f2b(float f) {  // RTN-even
    unsigned int u = __builtin_bit_cast(unsigned int, f);
    unsigned int lsb = (u >> 16) & 1u;
    u += 0x7fffu + lsb;
    return (unsigned short)(u >> 16);
}

__global__ void k_count(const int* __restrict__ dst, int* __restrict__ cnt, int E) {
    int e = blockIdx.x * blockDim.x + threadIdx.x;
    if (e < E) atomicAdd(&cnt[dst[e]], 1);
}

__global__ void k_dis(const int* __restrict__ cnt, float* __restrict__ dis, int n) {
    int i = blockIdx.x * blockDim.x + threadIdx.x;
    if (i < n) dis[i] = rsqrtf((float)cnt[i] + 1.0f);  // +1 self-loop => deg>=1
}

// --- exclusive-scan machinery (2048 items per block) -----------------------
__global__ void k_scan1(const int* __restrict__ in, int* __restrict__ out1,
                        int* __restrict__ bsum, int n) {
    __shared__ int s[256];
    int t = threadIdx.x;
    int base = blockIdx.x * 2048 + t * 8;
    int v[8];
    int run = 0;
#pragma unroll
    for (int i = 0; i < 8; ++i) {
        int idx = base + i;
        int x = (idx < n) ? in[idx] : 0;
        run += x;
        v[i] = run;
    }
    s[t] = run;
    __syncthreads();
    for (int off = 1; off < 256; off <<= 1) {
        int add = (t >= off) ? s[t - off] : 0;
        __syncthreads();
        s[t] += add;
        __syncthreads();
    }
    int pre = (t > 0) ? s[t - 1] : 0;
#pragma unroll
    for (int i = 0; i < 8; ++i) {
        int idx = base + i;
        if (idx < n) out1[idx] = v[i] + pre;
    }
    if (t == 255) bsum[blockIdx.x] = s[255];
}

__global__ void k_scan2(int* bsum, int nb) {
    __shared__ int s[256];
    int t = threadIdx.x;
    s[t] = (t < nb) ? bsum[t] : 0;
    __syncthreads();
    for (int off = 1; off < 256; off <<= 1) {
        int add = (t >= off) ? s[t - off] : 0;
        __syncthreads();
        s[t] += add;
        __syncthreads();
    }
    if (t < nb) bsum[t] = s[t];
}

__global__ void k_scan3(int* __restrict__ rowstart, const int* __restrict__ bsum, int n) {
    int b = blockIdx.x, t = threadIdx.x;
    if (b == 0) {
        if (t == 0) rowstart[0] = 0;
        return;
    }
    int add = bsum[b - 1];
    int* out1 = rowstart + 1;
    int base = b * 2048 + t * 8;
#pragma unroll
    for (int i = 0; i < 8; ++i) {
        int idx = base + i;
        if (idx < n) out1[idx] += add;
    }
}

__global__ void k_fill(const int* __restrict__ src, const int* __restrict__ dst,
                       int* __restrict__ cursor, int* __restrict__ csr_src, int E) {
    int e = blockIdx.x * blockDim.x + threadIdx.x;
    if (e >= E) return;
    int d = dst[e];
    int pos = atomicAdd(&cursor[d], 1);
    csr_src[pos] = src[e];
}

// --- pack W (Ksrc x 128 fp32) into MFMA B-fragment layout, bf16, K padded ---
__global__ void k_cvtw(const float* __restrict__ W, unsigned short* __restrict__ out,
                       int Ksrc, int KS) {
    int tid = blockIdx.x * blockDim.x + threadIdx.x;
    if (tid >= KS * 512) return;
    int lane = tid & 63, f = tid >> 6;
    int m = f >> 3, ct = f & 7;
    int col = ct * 16 + (lane & 15);
    int kb = m * 32 + ((lane >> 4) << 3);
    unsigned short v[8];
#pragma unroll
    for (int j = 0; j < 8; ++j) {
        int k = kb + j;
        v[j] = (k < Ksrc) ? f2b(W[k * 128 + col]) : (unsigned short)0;
    }
    short8* o = (short8*)(out + (size_t)tid * 8);
    *o = *(short8*)v;
}

// --- fused GCN layer --------------------------------------------------------
// Phase 1: wave per row (8 waves x 16 rows = 128-row tile), fp32 accumulation
//          over self + CSR neighbors, pack bf16 -> LDS (swizzled).
// Phase 2: MFMA 16x16x32 from LDS A-fragments x packed-W B-fragments.
// L0: input = fp32 x (N x 82), dis applied on the fly (K padded to 96).
// else: input = bf16 (N x 128), dis-prescaled by previous epilogue.
// SCALE: out *= dis[row] (pre-scale for next layer's aggregation).
// GATE: fused gate dot -> gate[row].
template <int KS, bool L0, bool SCALE, bool GATE>
__global__ __launch_bounds__(512) void k_layer(
    const void* __restrict__ hin, const float* __restrict__ dis,
    const int* __restrict__ rowstart, const int* __restrict__ csr,
    const unsigned short* __restrict__ Wp, const float* __restrict__ bias,
    unsigned short* __restrict__ out, const float* __restrict__ gw,
    const float* __restrict__ gb, float* __restrict__ gate, int n) {
    constexpr int K = KS * 32;
    __shared__ unsigned int As[128 * 64];  // 128 rows x 256B, zero-padded
    int t = threadIdx.x, lane = t & 63, w = t >> 6;
    int tile = blockIdx.x * 128;

    // ---- phase 1: aggregate 16 rows per wave ----
    for (int i = 0; i < 16; ++i) {
        int r = (w << 4) + i;  // LDS row 0..127
        int v = tile + r;
        float a0 = 0.f, a1 = 0.f;
        if (v < n) {
            if constexpr (L0) {
                const float* x = (const float*)hin;
                int c0 = lane * 2;
                float dv = dis[v];
                if (c0 < 82) {
                    float2 xv = *(const float2*)(x + (size_t)v * 82 + c0);
                    a0 = dv * xv.x;
                    a1 = dv * xv.y;
                }
                int e0 = rowstart[v], e1 = rowstart[v + 1];
                for (int e = e0; e < e1; ++e) {
                    int u = csr[e];
                    float du = dis[u];
                    if (c0 < 82) {
                        float2 xu = *(const float2*)(x + (size_t)u * 82 + c0);
                        a0 = fmaf(du, xu.x, a0);
                        a1 = fmaf(du, xu.y, a1);
                    }
                }
            } else {
                const unsigned short* hd = (const unsigned short*)hin;
                unsigned int hv = ((const unsigned int*)(hd + (size_t)v * K))[lane];
                a0 = b2f(hv << 16);
                a1 = b2f(hv & 0xffff0000u);
                int e0 = rowstart[v], e1 = rowstart[v + 1];
                for (int e = e0; e < e1; ++e) {
                    int u = csr[e];
                    unsigned int hu = ((const unsigned int*)(hd + (size_t)u * K))[lane];
                    a0 += b2f(hu << 16);
                    a1 += b2f(hu & 0xffff0000u);
                }
            }
            float dv = dis[v];
            a0 *= dv;
            a1 *= dv;
        }
        unsigned int packed = ((unsigned int)f2b(a1) << 16) | f2b(a0);
        As[(r << 6) + (lane ^ ((i & 7) << 2))] = packed;  // swizzled write
    }
    __syncthreads();

    // ---- phase 2: MFMA, wave = 16 rows ----
    int r0 = lane & 15, ch = lane >> 4;
    int myrow = (w << 4) + r0;
    const unsigned int* arow = &As[myrow << 6];
    f32x4 acc[8];
#pragma unroll
    for (int ct = 0; ct < 8; ++ct) acc[ct] = (f32x4){0.f, 0.f, 0.f, 0.f};
#pragma unroll
    for (int m = 0; m < KS; ++m) {
        int slot = (ch + 4 * m) ^ (r0 & 7);
        short8 a = *(const short8*)(arow + slot * 4);
        const short8* wf = (const short8*)Wp + ((size_t)(m * 8) * 64 + lane);
#pragma unroll
        for (int ct = 0; ct < 8; ++ct) {
            short8 b = wf[ct * 64];
            acc[ct] = __builtin_amdgcn_mfma_f32_16x16x32_bf16(a, b, acc[ct], 0, 0, 0);
        }
    }

    // ---- epilogue ----
    int cq = r0;
    float bb[8], gwv[8];
#pragma unroll
    for (int ct = 0; ct < 8; ++ct) {
        bb[ct] = bias[ct * 16 + cq];
        if (GATE) gwv[ct] = gw[ct * 16 + cq];
    }
    float gbv = GATE ? gb[0] : 0.f;
    int rbase = tile + (w << 4) + (ch << 2);
#pragma unroll
    for (int reg = 0; reg < 4; ++reg) {
        int row = rbase + reg;
        bool ok = row < n;
        float dv = (SCALE && ok) ? dis[row] : 1.f;
        float gp = 0.f;
#pragma unroll
        for (int ct = 0; ct < 8; ++ct) {
            float o = fmaxf(acc[ct][reg] + bb[ct], 0.f);
            if (GATE) gp = fmaf(o, gwv[ct], gp);
            if (ok) out[(size_t)row * 128 + ct * 16 + cq] = f2b(SCALE ? o * dv : o);
        }
        if (GATE) {
            gp += __shfl_xor(gp, 1);
            gp += __shfl_xor(gp, 2);
            gp += __shfl_xor(gp, 4);
            gp += __shfl_xor(gp, 8);
            if (cq == 0 && ok) gate[row] = gp + gbv;
        }
    }
}

// --- graph boundaries on sorted batch via binary search ---------------------
__global__ void k_bounds(const int* __restrict__ batch, int* __restrict__ goff,
                         int n, int B) {
    int g = blockIdx.x * blockDim.x + threadIdx.x;
    if (g > B) return;
    int lo = 0, hi = n;
    while (lo < hi) {
        int mid = (lo + hi) >> 1;
        if (batch[mid] < g) lo = mid + 1;
        else hi = mid;
    }
    goff[g] = lo;
}

// --- attention pooling: one wave per graph; h is bf16 -----------------------
__global__ __launch_bounds__(256) void k_pool(const unsigned short* __restrict__ h,
                                              const float* __restrict__ gate,
                                              const int* __restrict__ goff,
                                              float* __restrict__ emb, int B) {
    int wid = (blockIdx.x * blockDim.x + threadIdx.x) >> 6;
    int lane = threadIdx.x & 63;
    if (wid >= B) return;
    int s = goff[wid], e2 = goff[wid + 1];
    float* ev2 = emb + (size_t)wid * 128 + lane * 2;
    if (s >= e2) {
        ev2[0] = 0.f;
        ev2[1] = 0.f;
        return;
    }
    float m = -INFINITY;
    for (int v = s + lane; v < e2; v += 64) m = fmaxf(m, gate[v]);
#pragma unroll
    for (int off = 32; off; off >>= 1) m = fmaxf(m, __shfl_xor(m, off));
    float a0 = 0.f, a1 = 0.f, den = 0.f;
    for (int v = s; v < e2; ++v) {
        float ev = __expf(gate[v] - m);
        den += ev;
        unsigned int hv = *(const unsigned int*)((const char*)h + (size_t)v * 256 + lane * 4);
        a0 = fmaf(ev, b2f(hv << 16), a0);
        a1 = fmaf(ev, b2f(hv & 0xffff0000u), a1);
    }
    float inv = 1.f / den;
    ev2[0] = a0 * inv;
    ev2[1] = a1 * inv;
}

// --- final projection: 32 graphs per block ----------------------------------
__global__ __launch_bounds__(256) void k_proj(const float* __restrict__ emb,
                                              const float* __restrict__ pw,
                                              const float* __restrict__ pb,
                                              float* __restrict__ out, int B) {
    __shared__ float es[32][128];
    int g0 = blockIdx.x * 32;
    int t = threadIdx.x;
    for (int i = t; i < 1024; i += 256) {  // 32 rows x 32 float4
        int g = g0 + (i >> 5);
        float4 val = (g < B) ? ((const float4*)emb)[(size_t)g * 32 + (i & 31)]
                             : make_float4(0.f, 0.f, 0.f, 0.f);
        *(float4*)&es[i >> 5][(i & 31) * 4] = val;
    }
    __syncthreads();
    float acc[32];
#pragma unroll
    for (int i = 0; i < 32; ++i) acc[i] = 0.f;
    for (int k = 0; k < 128; ++k) {
        float wv = pw[k * 256 + t];
#pragma unroll
        for (int i = 0; i < 32; ++i) acc[i] = fmaf(es[i][k], wv, acc[i]);
    }
    float b = pb[t];
#pragma unroll
    for (int i = 0; i < 32; ++i) {
        int g = g0 + i;
        if (g < B) out[(size_t)g * 256 + t] = acc[i] + b;
    }
}

// ---------------------------------------------------------------------------
extern "C" void kernel_launch(void* const* d_in, const int* in_sizes, int n_in,
                              void* d_out, int out_size, void* d_ws, size_t ws_size,
                              hipStream_t stream) {
    const float* x = (const float*)d_in[0];
    const int* ei = (const int*)d_in[1];
    const int* batch = (const int*)d_in[2];
    const float* W0 = (const float*)d_in[3];
    const float* b0 = (const float*)d_in[4];
    const float* W1 = (const float*)d_in[5];
    const float* b1 = (const float*)d_in[6];
    const float* W2 = (const float*)d_in[7];
    const float* b2 = (const float*)d_in[8];
    const float* gw = (const float*)d_in[9];
    const float* gb = (const float*)d_in[10];
    const float* pw = (const float*)d_in[11];
    const float* pb = (const float*)d_in[12];
    float* out = (float*)d_out;

    const int N = in_sizes[2];
    const int E = in_sizes[1] / 2;
    const int B = out_size / 256;
    (void)n_in;

    const int* esrc = ei;
    const int* edst = ei + E;

    char* p = (char*)d_ws;
    auto carve = [&](size_t bytes) {
        char* r = p;
        p += (bytes + 255) & ~(size_t)255;
        return r;
    };
    unsigned short* hA = (unsigned short*)carve((size_t)N * 128 * 2);
    unsigned short* hB = (unsigned short*)carve((size_t)N * 128 * 2);
    float* emb = (float*)carve((size_t)B * 128 * 4);
    int* csr_src = (int*)carve((size_t)E * 4);
    float* dis = (float*)carve((size_t)N * 4);
    int* cnt = (int*)carve((size_t)N * 4);
    int* rowstart = (int*)carve((size_t)(N + 1) * 4);
    int* cursor = (int*)carve((size_t)N * 4);
    float* gate = (float*)carve((size_t)N * 4);
    int* goff = (int*)carve((size_t)(B + 1) * 4);
    int* bsum = (int*)carve((size_t)4096 * 4);
    unsigned short* wp0 = (unsigned short*)carve((size_t)3 * 512 * 8 * 2);
    unsigned short* wp1 = (unsigned short*)carve((size_t)4 * 512 * 8 * 2);
    unsigned short* wp2 = (unsigned short*)carve((size_t)4 * 512 * 8 * 2);
    if ((size_t)(p - (char*)d_ws) > ws_size) return;

    const int nb = (N + 2047) / 2048;

    hipMemsetAsync(cnt, 0, (size_t)N * 4, stream);
    k_count<<<(E + 255) / 256, 256, 0, stream>>>(edst, cnt, E);
    k_dis<<<(N + 255) / 256, 256, 0, stream>>>(cnt, dis, N);
    k_scan1<<<nb, 256, 0, stream>>>(cnt, rowstart + 1, bsum, N);
    k_scan2<<<1, 256, 0, stream>>>(bsum, nb);
    k_scan3<<<nb, 256, 0, stream>>>(rowstart, bsum, N);
    hipMemcpyAsync(cursor, rowstart, (size_t)N * 4, hipMemcpyDeviceToDevice, stream);
    k_fill<<<(E + 255) / 256, 256, 0, stream>>>(esrc, edst, cursor, csr_src, E);

    k_cvtw<<<6, 256, 0, stream>>>(W0, wp0, 82, 3);
    k_cvtw<<<8, 256, 0, stream>>>(W1, wp1, 128, 4);
    k_cvtw<<<8, 256, 0, stream>>>(W2, wp2, 128, 4);

    const int blocks = (N + 127) / 128;

    // layer 0: x (fp32) -> hA (bf16, dis-prescaled)
    k_layer<3, true, true, false><<<blocks, 512, 0, stream>>>(
        x, dis, rowstart, csr_src, wp0, b0, hA, nullptr, nullptr, nullptr, N);
    // layer 1: hA -> hB (bf16, dis-prescaled)
    k_layer<4, false, true, false><<<blocks, 512, 0, stream>>>(
        hA, dis, rowstart, csr_src, wp1, b1, hB, nullptr, nullptr, nullptr, N);
    // layer 2: hB -> hA (unscaled) + gate
    k_layer<4, false, false, true><<<blocks, 512, 0, stream>>>(
        hB, dis, rowstart, csr_src, wp2, b2, hA, gw, gb, gate, N);

    // pooling + projection
    k_bounds<<<(B + 1 + 255) / 256, 256, 0, stream>>>(batch, goff, N, B);
    k_pool<<<(B + 3) / 4, 256, 0, stream>>>(hA, gate, goff, emb, B);
    k_proj<<<(B + 31) / 32, 256, 0, stream>>>(emb, pw, pb, out, B);
}

// Round 5
// 859.924 us; speedup vs baseline: 1.2656x; 1.2656x over previous
//
#include <hip/hip_runtime.h>
#include <hip/hip_bf16.h>
#include <cstdint>

// ---------------------------------------------------------------------------
// MolGraphEncoder r5: split agg/mm (r3 structure), with (1) bf16 dis-prescaled
// x (xd) so all 3 aggregations are pure bf16 row-sums, and (2) 4-node-per-wave
// ILP in the aggregation gather loop (4x outstanding loads).
// ---------------------------------------------------------------------------

typedef __attribute__((ext_vector_type(8))) short short8;
typedef __attribute__((ext_vector_type(4))) float f32x4;

__device__ __forceinline__ float b2f(unsigned int hi16) {
    return __builtin_bit_cast(float, hi16);
}
__device__ __forceinline__ unsigned short f2b(float f) {  // RTN-even
    unsigned int u = __builtin_bit_cast(unsigned int, f);
    unsigned int lsb = (u >> 16) & 1u;
    u += 0x7fffu + lsb;
    return (unsigned short)(u >> 16);
}
__device__ __forceinline__ unsigned int packbf(float lo, float hi) {
    return ((unsigned int)f2b(hi) << 16) | f2b(lo);
}

__global__ void k_count(const int* __restrict__ dst, int* __restrict__ cnt, int E) {
    int e = blockIdx.x * blockDim.x + threadIdx.x;
    if (e < E) atomicAdd(&cnt[dst[e]], 1);
}

__global__ void k_dis(const int* __restrict__ cnt, float* __restrict__ dis, int n) {
    int i = blockIdx.x * blockDim.x + threadIdx.x;
    if (i < n) dis[i] = rsqrtf((float)cnt[i] + 1.0f);  // +1 self-loop => deg>=1
}

// --- exclusive-scan machinery (2048 items per block) -----------------------
__global__ void k_scan1(const int* __restrict__ in, int* __restrict__ out1,
                        int* __restrict__ bsum, int n) {
    __shared__ int s[256];
    int t = threadIdx.x;
    int base = blockIdx.x * 2048 + t * 8;
    int v[8];
    int run = 0;
#pragma unroll
    for (int i = 0; i < 8; ++i) {
        int idx = base + i;
        int x = (idx < n) ? in[idx] : 0;
        run += x;
        v[i] = run;
    }
    s[t] = run;
    __syncthreads();
    for (int off = 1; off < 256; off <<= 1) {
        int add = (t >= off) ? s[t - off] : 0;
        __syncthreads();
        s[t] += add;
        __syncthreads();
    }
    int pre = (t > 0) ? s[t - 1] : 0;
#pragma unroll
    for (int i = 0; i < 8; ++i) {
        int idx = base + i;
        if (idx < n) out1[idx] = v[i] + pre;
    }
    if (t == 255) bsum[blockIdx.x] = s[255];
}

__global__ void k_scan2(int* bsum, int nb) {
    __shared__ int s[256];
    int t = threadIdx.x;
    s[t] = (t < nb) ? bsum[t] : 0;
    __syncthreads();
    for (int off = 1; off < 256; off <<= 1) {
        int add = (t >= off) ? s[t - off] : 0;
        __syncthreads();
        s[t] += add;
        __syncthreads();
    }
    if (t < nb) bsum[t] = s[t];
}

__global__ void k_scan3(int* __restrict__ rowstart, const int* __restrict__ bsum, int n) {
    int b = blockIdx.x, t = threadIdx.x;
    if (b == 0) {
        if (t == 0) rowstart[0] = 0;
        return;
    }
    int add = bsum[b - 1];
    int* out1 = rowstart + 1;
    int base = b * 2048 + t * 8;
#pragma unroll
    for (int i = 0; i < 8; ++i) {
        int idx = base + i;
        if (idx < n) out1[idx] += add;
    }
}

__global__ void k_fill(const int* __restrict__ src, const int* __restrict__ dst,
                       int* __restrict__ cursor, int* __restrict__ csr_src, int E) {
    int e = blockIdx.x * blockDim.x + threadIdx.x;
    if (e >= E) return;
    int d = dst[e];
    int pos = atomicAdd(&cursor[d], 1);
    csr_src[pos] = src[e];
}

// --- pack W (Ksrc x 128 fp32) into MFMA B-fragment layout, bf16, K padded ---
__global__ void k_cvtw(const float* __restrict__ W, unsigned short* __restrict__ out,
                       int Ksrc, int KS) {
    int tid = blockIdx.x * blockDim.x + threadIdx.x;
    if (tid >= KS * 512) return;
    int lane = tid & 63, f = tid >> 6;
    int m = f >> 3, ct = f & 7;
    int col = ct * 16 + (lane & 15);
    int kb = m * 32 + ((lane >> 4) << 3);
    unsigned short v[8];
#pragma unroll
    for (int j = 0; j < 8; ++j) {
        int k = kb + j;
        v[j] = (k < Ksrc) ? f2b(W[k * 128 + col]) : (unsigned short)0;
    }
    short8* o = (short8*)(out + (size_t)tid * 8);
    *o = *(short8*)v;
}

// --- xd = bf16(dis[v] * x[v]), 82 cols padded to 96 (48 u32/row) ------------
__global__ __launch_bounds__(256) void k_xd(const float* __restrict__ x,
                                            const float* __restrict__ dis,
                                            unsigned int* __restrict__ xd, int n) {
    int tid = blockIdx.x * blockDim.x + threadIdx.x;
    if (tid >= n * 48) return;
    int v = tid / 48;
    int c = (tid - v * 48) * 2;
    float dv = dis[v];
    const float* xv = x + (size_t)v * 82;
    float fx = (c < 82) ? dv * xv[c] : 0.f;
    float fy = (c + 1 < 82) ? dv * xv[c + 1] : 0.f;
    xd[tid] = packbf(fx, fy);
}

// --- aggregation: 4 consecutive nodes per wave, lane-per-u32-column ---------
// in/out rows are RU u32 (2 bf16 each). agg[v] = dis[v]*(in[v] + sum in[u]).
template <int RU>
__global__ __launch_bounds__(256) void k_agg(
    const unsigned int* __restrict__ hd, const float* __restrict__ dis,
    const int* __restrict__ rowstart, const int* __restrict__ csr,
    unsigned int* __restrict__ agg, int n) {
    int wid = (blockIdx.x * blockDim.x + threadIdx.x) >> 6;
    int lane = threadIdx.x & 63;
    int nw = (gridDim.x * blockDim.x) >> 6;
    const bool act = (RU == 64) ? true : (lane < RU);
    const int li = act ? lane : 0;

    for (int v0 = wid * 4; v0 < n; v0 += nw * 4) {
        int nv = n - v0;
        if (nv > 4) nv = 4;
        int e0 = rowstart[v0];
        int eE = rowstart[v0 + nv];
        int b1 = (nv > 1) ? rowstart[v0 + 1] : eE;
        int b2 = (nv > 2) ? rowstart[v0 + 2] : eE;
        int b3 = (nv > 3) ? rowstart[v0 + 3] : eE;

        // self terms (4 independent loads in flight)
        unsigned int s0 = hd[(size_t)v0 * RU + li];
        unsigned int s1 = (nv > 1) ? hd[(size_t)(v0 + 1) * RU + li] : 0u;
        unsigned int s2 = (nv > 2) ? hd[(size_t)(v0 + 2) * RU + li] : 0u;
        unsigned int s3 = (nv > 3) ? hd[(size_t)(v0 + 3) * RU + li] : 0u;
        float a0x = b2f(s0 << 16), a0y = b2f(s0 & 0xffff0000u);
        float a1x = b2f(s1 << 16), a1y = b2f(s1 & 0xffff0000u);
        float a2x = b2f(s2 << 16), a2y = b2f(s2 & 0xffff0000u);
        float a3x = b2f(s3 << 16), a3y = b2f(s3 & 0xffff0000u);

        for (int e = e0; e < eE; e += 4) {
            int rem = eE - e;
            int u0 = csr[e];
            int u1 = (rem > 1) ? csr[e + 1] : u0;
            int u2 = (rem > 2) ? csr[e + 2] : u0;
            int u3 = (rem > 3) ? csr[e + 3] : u0;
            unsigned int r0 = hd[(size_t)u0 * RU + li];
            unsigned int r1 = (rem > 1) ? hd[(size_t)u1 * RU + li] : 0u;
            unsigned int r2 = (rem > 2) ? hd[(size_t)u2 * RU + li] : 0u;
            unsigned int r3 = (rem > 3) ? hd[(size_t)u3 * RU + li] : 0u;
#define ACC(r, ei)                                                    \
            {                                                         \
                float fx = b2f((r) << 16), fy = b2f((r) & 0xffff0000u); \
                if ((ei) < b1) { a0x += fx; a0y += fy; }              \
                else if ((ei) < b2) { a1x += fx; a1y += fy; }         \
                else if ((ei) < b3) { a2x += fx; a2y += fy; }         \
                else { a3x += fx; a3y += fy; }                        \
            }
            ACC(r0, e)
            if (rem > 1) ACC(r1, e + 1)
            if (rem > 2) ACC(r2, e + 2)
            if (rem > 3) ACC(r3, e + 3)
#undef ACC
        }

        if (act) {
            float d0 = dis[v0];
            agg[(size_t)v0 * RU + lane] = packbf(d0 * a0x, d0 * a0y);
            if (nv > 1) {
                float d1 = dis[v0 + 1];
                agg[(size_t)(v0 + 1) * RU + lane] = packbf(d1 * a1x, d1 * a1y);
            }
            if (nv > 2) {
                float d2 = dis[v0 + 2];
                agg[(size_t)(v0 + 2) * RU + lane] = packbf(d2 * a2x, d2 * a2y);
            }
            if (nv > 3) {
                float d3 = dis[v0 + 3];
                agg[(size_t)(v0 + 3) * RU + lane] = packbf(d3 * a3x, d3 * a3y);
            }
        }
    }
}

// --- MFMA GEMM: out(bf16 Nx128) = epi( A(bf16 NxKp) @ Wp + b ) --------------
template <int Kp, bool SCALE, bool GATE>
__global__ __launch_bounds__(256) void k_mm(
    const unsigned short* __restrict__ A, const unsigned short* __restrict__ Wp,
    const float* __restrict__ bias, const float* __restrict__ dis,
    unsigned short* __restrict__ out, const float* __restrict__ gw,
    const float* __restrict__ gb, float* __restrict__ gate, int n) {
    constexpr int KS = Kp / 32;
    int t = threadIdx.x, lane = t & 63, w = t >> 6;
    int base = blockIdx.x * 128 + w * 32;
    if (base >= n) return;
    int r0 = lane & 15, ch = lane >> 4;
    int row0 = base + r0, row1 = base + 16 + r0;
    if (row0 >= n) row0 = n - 1;
    if (row1 >= n) row1 = n - 1;
    const char* pa0 = (const char*)A + (size_t)row0 * (Kp * 2) + ch * 16;
    const char* pa1 = (const char*)A + (size_t)row1 * (Kp * 2) + ch * 16;

    f32x4 z = {0.f, 0.f, 0.f, 0.f};
    f32x4 acc0[8], acc1[8];
#pragma unroll
    for (int ct = 0; ct < 8; ++ct) { acc0[ct] = z; acc1[ct] = z; }

#pragma unroll
    for (int m = 0; m < KS; ++m) {
        short8 a0 = *(const short8*)(pa0 + m * 64);
        short8 a1 = *(const short8*)(pa1 + m * 64);
        const short8* wf = (const short8*)Wp + (size_t)(m * 8) * 64 + lane;
#pragma unroll
        for (int ct = 0; ct < 8; ++ct) {
            short8 b = wf[ct * 64];
            acc0[ct] = __builtin_amdgcn_mfma_f32_16x16x32_bf16(a0, b, acc0[ct], 0, 0, 0);
            acc1[ct] = __builtin_amdgcn_mfma_f32_16x16x32_bf16(a1, b, acc1[ct], 0, 0, 0);
        }
    }

    int cq = lane & 15;
    float bb[8], gwv[8];
#pragma unroll
    for (int ct = 0; ct < 8; ++ct) {
        bb[ct] = bias[ct * 16 + cq];
        if (GATE) gwv[ct] = gw[ct * 16 + cq];
    }
    float gbv = GATE ? gb[0] : 0.f;

#pragma unroll
    for (int s = 0; s < 2; ++s) {
#pragma unroll
        for (int reg = 0; reg < 4; ++reg) {
            int row = base + s * 16 + ((lane >> 4) << 2) + reg;
            bool ok = row < n;
            float dv = (SCALE && ok) ? dis[row] : 1.f;
            float gp = 0.f;
#pragma unroll
            for (int ct = 0; ct < 8; ++ct) {
                float o = (s == 0) ? acc0[ct][reg] : acc1[ct][reg];
                o = fmaxf(o + bb[ct], 0.f);
                if (GATE) gp = fmaf(o, gwv[ct], gp);
                if (ok) out[(size_t)row * 128 + ct * 16 + cq] = f2b(SCALE ? o * dv : o);
            }
            if (GATE) {
                gp += __shfl_xor(gp, 1);
                gp += __shfl_xor(gp, 2);
                gp += __shfl_xor(gp, 4);
                gp += __shfl_xor(gp, 8);
                if (cq == 0 && ok) gate[row] = gp + gbv;
            }
        }
    }
}

// --- graph boundaries on sorted batch via binary search ---------------------
__global__ void k_bounds(const int* __restrict__ batch, int* __restrict__ goff,
                         int n, int B) {
    int g = blockIdx.x * blockDim.x + threadIdx.x;
    if (g > B) return;
    int lo = 0, hi = n;
    while (lo < hi) {
        int mid = (lo + hi) >> 1;
        if (batch[mid] < g) lo = mid + 1;
        else hi = mid;
    }
    goff[g] = lo;
}

// --- attention pooling: one wave per graph; h is bf16 -----------------------
__global__ __launch_bounds__(256) void k_pool(const unsigned short* __restrict__ h,
                                              const float* __restrict__ gate,
                                              const int* __restrict__ goff,
                                              float* __restrict__ emb, int B) {
    int wid = (blockIdx.x * blockDim.x + threadIdx.x) >> 6;
    int lane = threadIdx.x & 63;
    if (wid >= B) return;
    int s = goff[wid], e2 = goff[wid + 1];
    float* ev2 = emb + (size_t)wid * 128 + lane * 2;
    if (s >= e2) {
        ev2[0] = 0.f;
        ev2[1] = 0.f;
        return;
    }
    float m = -INFINITY;
    for (int v = s + lane; v < e2; v += 64) m = fmaxf(m, gate[v]);
#pragma unroll
    for (int off = 32; off; off >>= 1) m = fmaxf(m, __shfl_xor(m, off));
    float a0 = 0.f, a1 = 0.f, den = 0.f;
    for (int v = s; v < e2; ++v) {
        float ev = __expf(gate[v] - m);
        den += ev;
        unsigned int hv = *(const unsigned int*)((const char*)h + (size_t)v * 256 + lane * 4);
        a0 = fmaf(ev, b2f(hv << 16), a0);
        a1 = fmaf(ev, b2f(hv & 0xffff0000u), a1);
    }
    float inv = 1.f / den;
    ev2[0] = a0 * inv;
    ev2[1] = a1 * inv;
}

// --- final projection: 32 graphs per block ----------------------------------
__global__ __launch_bounds__(256) void k_proj(const float* __restrict__ emb,
                                              const float* __restrict__ pw,
                                              const float* __restrict__ pb,
                                              float* __restrict__ out, int B) {
    __shared__ float es[32][128];
    int g0 = blockIdx.x * 32;
    int t = threadIdx.x;
    for (int i = t; i < 1024; i += 256) {
        int g = g0 + (i >> 5);
        float4 val = (g < B) ? ((const float4*)emb)[(size_t)g * 32 + (i & 31)]
                             : make_float4(0.f, 0.f, 0.f, 0.f);
        *(float4*)&es[i >> 5][(i & 31) * 4] = val;
    }
    __syncthreads();
    float acc[32];
#pragma unroll
    for (int i = 0; i < 32; ++i) acc[i] = 0.f;
    for (int k = 0; k < 128; ++k) {
        float wv = pw[k * 256 + t];
#pragma unroll
        for (int i = 0; i < 32; ++i) acc[i] = fmaf(es[i][k], wv, acc[i]);
    }
    float b = pb[t];
#pragma unroll
    for (int i = 0; i < 32; ++i) {
        int g = g0 + i;
        if (g < B) out[(size_t)g * 256 + t] = acc[i] + b;
    }
}

// ---------------------------------------------------------------------------
extern "C" void kernel_launch(void* const* d_in, const int* in_sizes, int n_in,
                              void* d_out, int out_size, void* d_ws, size_t ws_size,
                              hipStream_t stream) {
    const float* x = (const float*)d_in[0];
    const int* ei = (const int*)d_in[1];
    const int* batch = (const int*)d_in[2];
    const float* W0 = (const float*)d_in[3];
    const float* b0 = (const float*)d_in[4];
    const float* W1 = (const float*)d_in[5];
    const float* b1 = (const float*)d_in[6];
    const float* W2 = (const float*)d_in[7];
    const float* b2 = (const float*)d_in[8];
    const float* gw = (const float*)d_in[9];
    const float* gb = (const float*)d_in[10];
    const float* pw = (const float*)d_in[11];
    const float* pb = (const float*)d_in[12];
    float* out = (float*)d_out;

    const int N = in_sizes[2];
    const int E = in_sizes[1] / 2;
    const int B = out_size / 256;
    (void)n_in;

    const int* esrc = ei;
    const int* edst = ei + E;

    char* p = (char*)d_ws;
    auto carve = [&](size_t bytes) {
        char* r = p;
        p += (bytes + 255) & ~(size_t)255;
        return r;
    };
    unsigned int* xd = (unsigned int*)carve((size_t)N * 48 * 4);
    unsigned int* aggbuf = (unsigned int*)carve((size_t)N * 64 * 4);
    unsigned int* hbuf = (unsigned int*)carve((size_t)N * 64 * 4);
    float* emb = (float*)carve((size_t)B * 128 * 4);
    int* csr_src = (int*)carve((size_t)E * 4);
    float* dis = (float*)carve((size_t)N * 4);
    int* cnt = (int*)carve((size_t)N * 4);
    int* rowstart = (int*)carve((size_t)(N + 1) * 4);
    int* cursor = (int*)carve((size_t)N * 4);
    float* gate = (float*)carve((size_t)N * 4);
    int* goff = (int*)carve((size_t)(B + 1) * 4);
    int* bsum = (int*)carve((size_t)4096 * 4);
    unsigned short* wp0 = (unsigned short*)carve((size_t)3 * 512 * 8 * 2);
    unsigned short* wp1 = (unsigned short*)carve((size_t)4 * 512 * 8 * 2);
    unsigned short* wp2 = (unsigned short*)carve((size_t)4 * 512 * 8 * 2);
    if ((size_t)(p - (char*)d_ws) > ws_size) return;

    const int nb = (N + 2047) / 2048;

    hipMemsetAsync(cnt, 0, (size_t)N * 4, stream);
    k_count<<<(E + 255) / 256, 256, 0, stream>>>(edst, cnt, E);
    k_dis<<<(N + 255) / 256, 256, 0, stream>>>(cnt, dis, N);
    k_scan1<<<nb, 256, 0, stream>>>(cnt, rowstart + 1, bsum, N);
    k_scan2<<<1, 256, 0, stream>>>(bsum, nb);
    k_scan3<<<nb, 256, 0, stream>>>(rowstart, bsum, N);
    hipMemcpyAsync(cursor, rowstart, (size_t)N * 4, hipMemcpyDeviceToDevice, stream);
    k_fill<<<(E + 255) / 256, 256, 0, stream>>>(esrc, edst, cursor, csr_src, E);

    k_cvtw<<<6, 256, 0, stream>>>(W0, wp0, 82, 3);
    k_cvtw<<<8, 256, 0, stream>>>(W1, wp1, 128, 4);
    k_cvtw<<<8, 256, 0, stream>>>(W2, wp2, 128, 4);

    // xd = bf16(dis * x), padded to 96 cols
    k_xd<<<(N * 48 + 255) / 256, 256, 0, stream>>>(x, dis, xd, N);

    const int mm_blocks = (N + 127) / 128;

    // layer 0
    k_agg<48><<<2048, 256, 0, stream>>>(xd, dis, rowstart, csr_src, aggbuf, N);
    k_mm<96, true, false><<<mm_blocks, 256, 0, stream>>>(
        (const unsigned short*)aggbuf, wp0, b0, dis, (unsigned short*)hbuf,
        nullptr, nullptr, nullptr, N);
    // layer 1
    k_agg<64><<<2048, 256, 0, stream>>>(hbuf, dis, rowstart, csr_src, aggbuf, N);
    k_mm<128, true, false><<<mm_blocks, 256, 0, stream>>>(
        (const unsigned short*)aggbuf, wp1, b1, dis, (unsigned short*)hbuf,
        nullptr, nullptr, nullptr, N);
    // layer 2 (unscaled out + fused gate)
    k_agg<64><<<2048, 256, 0, stream>>>(hbuf, dis, rowstart, csr_src, aggbuf, N);
    k_mm<128, false, true><<<mm_blocks, 256, 0, stream>>>(
        (const unsigned short*)aggbuf, wp2, b2, dis, (unsigned short*)hbuf,
        gw, gb, gate, N);

    // pooling + projection
    k_bounds<<<(B + 1 + 255) / 256, 256, 0, stream>>>(batch, goff, N, B);
    k_pool<<<(B + 3) / 4, 256, 0, stream>>>((const unsigned short*)hbuf, gate, goff, emb, B);
    k_proj<<<(B + 31) / 32, 256, 0, stream>>>(emb, pw, pb, out, B);
}

// Round 6
// 752.745 us; speedup vs baseline: 1.4458x; 1.1424x over previous
//
#include <hip/hip_runtime.h>
#include <hip/hip_bf16.h>
#include <cstdint>

// ---------------------------------------------------------------------------
// MolGraphEncoder r6: fused per-layer kernel with r5's 4-node-ILP gather.
// Phase 1: 4 waves x 16 rows, bucketed 4-node gather (fp32 accum) -> bf16
//          XOR-swizzled LDS tile. Phase 2: 16-row MFMA strip per wave.
// No aggbuf round-trip; small blocks keep gather TLP (8 blocks/CU).
// ---------------------------------------------------------------------------

typedef __attribute__((ext_vector_type(8))) short short8;
typedef __attribute__((ext_vector_type(4))) float f32x4;

__device__ __forceinline__ float b2f(unsigned int hi16) {
    return __builtin_bit_cast(float, hi16);
}
__device__ __forceinline__ unsigned short f2b(float f) {  // RTN-even
    unsigned int u = __builtin_bit_cast(unsigned int, f);
    unsigned int lsb = (u >> 16) & 1u;
    u += 0x7fffu + lsb;
    return (unsigned short)(u >> 16);
}
__device__ __forceinline__ unsigned int packbf(float lo, float hi) {
    return ((unsigned int)f2b(hi) << 16) | f2b(lo);
}

__global__ void k_count(const int* __restrict__ dst, int* __restrict__ cnt, int E) {
    int e = blockIdx.x * blockDim.x + threadIdx.x;
    if (e < E) atomicAdd(&cnt[dst[e]], 1);
}

__global__ void k_dis(const int* __restrict__ cnt, float* __restrict__ dis, int n) {
    int i = blockIdx.x * blockDim.x + threadIdx.x;
    if (i < n) dis[i] = rsqrtf((float)cnt[i] + 1.0f);  // +1 self-loop => deg>=1
}

// --- exclusive-scan machinery (2048 items per block) -----------------------
__global__ void k_scan1(const int* __restrict__ in, int* __restrict__ out1,
                        int* __restrict__ bsum, int n) {
    __shared__ int s[256];
    int t = threadIdx.x;
    int base = blockIdx.x * 2048 + t * 8;
    int v[8];
    int run = 0;
#pragma unroll
    for (int i = 0; i < 8; ++i) {
        int idx = base + i;
        int x = (idx < n) ? in[idx] : 0;
        run += x;
        v[i] = run;
    }
    s[t] = run;
    __syncthreads();
    for (int off = 1; off < 256; off <<= 1) {
        int add = (t >= off) ? s[t - off] : 0;
        __syncthreads();
        s[t] += add;
        __syncthreads();
    }
    int pre = (t > 0) ? s[t - 1] : 0;
#pragma unroll
    for (int i = 0; i < 8; ++i) {
        int idx = base + i;
        if (idx < n) out1[idx] = v[i] + pre;
    }
    if (t == 255) bsum[blockIdx.x] = s[255];
}

__global__ void k_scan2(int* bsum, int nb) {
    __shared__ int s[256];
    int t = threadIdx.x;
    s[t] = (t < nb) ? bsum[t] : 0;
    __syncthreads();
    for (int off = 1; off < 256; off <<= 1) {
        int add = (t >= off) ? s[t - off] : 0;
        __syncthreads();
        s[t] += add;
        __syncthreads();
    }
    if (t < nb) bsum[t] = s[t];
}

__global__ void k_scan3(int* __restrict__ rowstart, const int* __restrict__ bsum, int n) {
    int b = blockIdx.x, t = threadIdx.x;
    if (b == 0) {
        if (t == 0) rowstart[0] = 0;
        return;
    }
    int add = bsum[b - 1];
    int* out1 = rowstart + 1;
    int base = b * 2048 + t * 8;
#pragma unroll
    for (int i = 0; i < 8; ++i) {
        int idx = base + i;
        if (idx < n) out1[idx] += add;
    }
}

__global__ void k_fill(const int* __restrict__ src, const int* __restrict__ dst,
                       int* __restrict__ cursor, int* __restrict__ csr_src, int E) {
    int e = blockIdx.x * blockDim.x + threadIdx.x;
    if (e >= E) return;
    int d = dst[e];
    int pos = atomicAdd(&cursor[d], 1);
    csr_src[pos] = src[e];
}

// --- pack W (Ksrc x 128 fp32) into MFMA B-fragment layout, bf16, K padded ---
__global__ void k_cvtw(const float* __restrict__ W, unsigned short* __restrict__ out,
                       int Ksrc, int KS) {
    int tid = blockIdx.x * blockDim.x + threadIdx.x;
    if (tid >= KS * 512) return;
    int lane = tid & 63, f = tid >> 6;
    int m = f >> 3, ct = f & 7;
    int col = ct * 16 + (lane & 15);
    int kb = m * 32 + ((lane >> 4) << 3);
    unsigned short v[8];
#pragma unroll
    for (int j = 0; j < 8; ++j) {
        int k = kb + j;
        v[j] = (k < Ksrc) ? f2b(W[k * 128 + col]) : (unsigned short)0;
    }
    short8* o = (short8*)(out + (size_t)tid * 8);
    *o = *(short8*)v;
}

// --- xd = bf16(dis[v] * x[v]), 82 cols padded to 96 (48 u32/row) ------------
__global__ __launch_bounds__(256) void k_xd(const float* __restrict__ x,
                                            const float* __restrict__ dis,
                                            unsigned int* __restrict__ xd, int n) {
    int tid = blockIdx.x * blockDim.x + threadIdx.x;
    if (tid >= n * 48) return;
    int v = tid / 48;
    int c = (tid - v * 48) * 2;
    float dv = dis[v];
    const float* xv = x + (size_t)v * 82;
    float fx = (c < 82) ? dv * xv[c] : 0.f;
    float fy = (c + 1 < 82) ? dv * xv[c + 1] : 0.f;
    xd[tid] = packbf(fx, fy);
}

// --- fused GCN layer: gather (4-node ILP) -> swizzled LDS -> MFMA -----------
// Input rows: RU = KS*16 u32 (2 bf16 each), dis-prescaled by producer.
// agg[v] = dis[v] * ( in[v] + sum_{u->v} in[u] );  out = relu(agg @ W + b)
// SCALE: out *= dis[row] (pre-scale for next layer). GATE: fused gate dot.
template <int KS, bool SCALE, bool GATE>
__global__ __launch_bounds__(256, 8) void k_fused(
    const unsigned int* __restrict__ hd, const float* __restrict__ dis,
    const int* __restrict__ rowstart, const int* __restrict__ csr,
    const unsigned short* __restrict__ Wp, const float* __restrict__ bias,
    unsigned short* __restrict__ out, const float* __restrict__ gw,
    const float* __restrict__ gb, float* __restrict__ gate, int n) {
    constexpr int RU = KS * 16;  // u32 per input row
    __shared__ unsigned int As[64 * 64];  // 64 rows x 256B (zero-padded), swizzled
    int t = threadIdx.x, lane = t & 63, w = t >> 6;
    int tile = blockIdx.x * 64;
    const bool act = (RU == 64) ? true : (lane < RU);
    const int li = act ? lane : 0;

    // ---- phase 1: each wave gathers 16 rows as 4 groups of 4 (ILP) ----
    for (int g = 0; g < 4; ++g) {
        int r = (w << 4) + g * 4;  // local row of first node in group
        int v0 = tile + r;
        unsigned int* dst0 = &As[(r + 0) * 64 + (lane ^ (((r + 0) & 7) << 2))];
        unsigned int* dst1 = &As[(r + 1) * 64 + (lane ^ (((r + 1) & 7) << 2))];
        unsigned int* dst2 = &As[(r + 2) * 64 + (lane ^ (((r + 2) & 7) << 2))];
        unsigned int* dst3 = &As[(r + 3) * 64 + (lane ^ (((r + 3) & 7) << 2))];
        if (v0 >= n) {
            *dst0 = 0u; *dst1 = 0u; *dst2 = 0u; *dst3 = 0u;
            continue;
        }
        int nv = n - v0;
        if (nv > 4) nv = 4;
        int e0 = rowstart[v0];
        int eE = rowstart[v0 + nv];
        int b1 = (nv > 1) ? rowstart[v0 + 1] : eE;
        int b2 = (nv > 2) ? rowstart[v0 + 2] : eE;
        int b3 = (nv > 3) ? rowstart[v0 + 3] : eE;

        unsigned int s0 = hd[(size_t)v0 * RU + li];
        unsigned int s1 = (nv > 1) ? hd[(size_t)(v0 + 1) * RU + li] : 0u;
        unsigned int s2 = (nv > 2) ? hd[(size_t)(v0 + 2) * RU + li] : 0u;
        unsigned int s3 = (nv > 3) ? hd[(size_t)(v0 + 3) * RU + li] : 0u;
        float a0x = b2f(s0 << 16), a0y = b2f(s0 & 0xffff0000u);
        float a1x = b2f(s1 << 16), a1y = b2f(s1 & 0xffff0000u);
        float a2x = b2f(s2 << 16), a2y = b2f(s2 & 0xffff0000u);
        float a3x = b2f(s3 << 16), a3y = b2f(s3 & 0xffff0000u);

        for (int e = e0; e < eE; e += 4) {
            int rem = eE - e;
            int u0 = csr[e];
            int u1 = (rem > 1) ? csr[e + 1] : u0;
            int u2 = (rem > 2) ? csr[e + 2] : u0;
            int u3 = (rem > 3) ? csr[e + 3] : u0;
            unsigned int r0v = hd[(size_t)u0 * RU + li];
            unsigned int r1v = (rem > 1) ? hd[(size_t)u1 * RU + li] : 0u;
            unsigned int r2v = (rem > 2) ? hd[(size_t)u2 * RU + li] : 0u;
            unsigned int r3v = (rem > 3) ? hd[(size_t)u3 * RU + li] : 0u;
#define ACC(rv, ei)                                                     \
            {                                                           \
                float fx = b2f((rv) << 16), fy = b2f((rv) & 0xffff0000u); \
                if ((ei) < b1) { a0x += fx; a0y += fy; }                \
                else if ((ei) < b2) { a1x += fx; a1y += fy; }           \
                else if ((ei) < b3) { a2x += fx; a2y += fy; }           \
                else { a3x += fx; a3y += fy; }                          \
            }
            ACC(r0v, e)
            if (rem > 1) ACC(r1v, e + 1)
            if (rem > 2) ACC(r2v, e + 2)
            if (rem > 3) ACC(r3v, e + 3)
#undef ACC
        }

        float d0 = dis[v0];
        float d1 = (nv > 1) ? dis[v0 + 1] : 0.f;
        float d2 = (nv > 2) ? dis[v0 + 2] : 0.f;
        float d3 = (nv > 3) ? dis[v0 + 3] : 0.f;
        *dst0 = act ? packbf(d0 * a0x, d0 * a0y) : 0u;
        *dst1 = (act && nv > 1) ? packbf(d1 * a1x, d1 * a1y) : 0u;
        *dst2 = (act && nv > 2) ? packbf(d2 * a2x, d2 * a2y) : 0u;
        *dst3 = (act && nv > 3) ? packbf(d3 * a3x, d3 * a3y) : 0u;
    }
    __syncthreads();

    // ---- phase 2: 16-row MFMA strip per wave ----
    int r0 = lane & 15, ch = lane >> 4;
    const unsigned int* arow = &As[((w << 4) + r0) << 6];
    f32x4 acc[8];
#pragma unroll
    for (int ct = 0; ct < 8; ++ct) acc[ct] = (f32x4){0.f, 0.f, 0.f, 0.f};
#pragma unroll
    for (int m = 0; m < KS; ++m) {
        int slot = (ch + 4 * m) ^ (r0 & 7);
        short8 a = *(const short8*)(arow + slot * 4);
        const short8* wf = (const short8*)Wp + ((size_t)(m * 8) * 64 + lane);
#pragma unroll
        for (int ct = 0; ct < 8; ++ct) {
            short8 b = wf[ct * 64];
            acc[ct] = __builtin_amdgcn_mfma_f32_16x16x32_bf16(a, b, acc[ct], 0, 0, 0);
        }
    }

    // ---- epilogue ----
    int cq = r0;
    float bb[8], gwv[8];
#pragma unroll
    for (int ct = 0; ct < 8; ++ct) {
        bb[ct] = bias[ct * 16 + cq];
        if (GATE) gwv[ct] = gw[ct * 16 + cq];
    }
    float gbv = GATE ? gb[0] : 0.f;
    int rbase = tile + (w << 4) + (ch << 2);
#pragma unroll
    for (int reg = 0; reg < 4; ++reg) {
        int row = rbase + reg;
        bool ok = row < n;
        float dv = (SCALE && ok) ? dis[row] : 1.f;
        float gp = 0.f;
#pragma unroll
        for (int ct = 0; ct < 8; ++ct) {
            float o = fmaxf(acc[ct][reg] + bb[ct], 0.f);
            if (GATE) gp = fmaf(o, gwv[ct], gp);
            if (ok) out[(size_t)row * 128 + ct * 16 + cq] = f2b(SCALE ? o * dv : o);
        }
        if (GATE) {
            gp += __shfl_xor(gp, 1);
            gp += __shfl_xor(gp, 2);
            gp += __shfl_xor(gp, 4);
            gp += __shfl_xor(gp, 8);
            if (cq == 0 && ok) gate[row] = gp + gbv;
        }
    }
}

// --- graph boundaries on sorted batch via binary search ---------------------
__global__ void k_bounds(const int* __restrict__ batch, int* __restrict__ goff,
                         int n, int B) {
    int g = blockIdx.x * blockDim.x + threadIdx.x;
    if (g > B) return;
    int lo = 0, hi = n;
    while (lo < hi) {
        int mid = (lo + hi) >> 1;
        if (batch[mid] < g) lo = mid + 1;
        else hi = mid;
    }
    goff[g] = lo;
}

// --- attention pooling: one wave per graph; h is bf16 -----------------------
__global__ __launch_bounds__(256) void k_pool(const unsigned short* __restrict__ h,
                                              const float* __restrict__ gate,
                                              const int* __restrict__ goff,
                                              float* __restrict__ emb, int B) {
    int wid = (blockIdx.x * blockDim.x + threadIdx.x) >> 6;
    int lane = threadIdx.x & 63;
    if (wid >= B) return;
    int s = goff[wid], e2 = goff[wid + 1];
    float* ev2 = emb + (size_t)wid * 128 + lane * 2;
    if (s >= e2) {
        ev2[0] = 0.f;
        ev2[1] = 0.f;
        return;
    }
    float m = -INFINITY;
    for (int v = s + lane; v < e2; v += 64) m = fmaxf(m, gate[v]);
#pragma unroll
    for (int off = 32; off; off >>= 1) m = fmaxf(m, __shfl_xor(m, off));
    float a0 = 0.f, a1 = 0.f, den = 0.f;
    for (int v = s; v < e2; ++v) {
        float ev = __expf(gate[v] - m);
        den += ev;
        unsigned int hv = *(const unsigned int*)((const char*)h + (size_t)v * 256 + lane * 4);
        a0 = fmaf(ev, b2f(hv << 16), a0);
        a1 = fmaf(ev, b2f(hv & 0xffff0000u), a1);
    }
    float inv = 1.f / den;
    ev2[0] = a0 * inv;
    ev2[1] = a1 * inv;
}

// --- final projection: 32 graphs per block ----------------------------------
__global__ __launch_bounds__(256) void k_proj(const float* __restrict__ emb,
                                              const float* __restrict__ pw,
                                              const float* __restrict__ pb,
                                              float* __restrict__ out, int B) {
    __shared__ float es[32][128];
    int g0 = blockIdx.x * 32;
    int t = threadIdx.x;
    for (int i = t; i < 1024; i += 256) {
        int g = g0 + (i >> 5);
        float4 val = (g < B) ? ((const float4*)emb)[(size_t)g * 32 + (i & 31)]
                             : make_float4(0.f, 0.f, 0.f, 0.f);
        *(float4*)&es[i >> 5][(i & 31) * 4] = val;
    }
    __syncthreads();
    float acc[32];
#pragma unroll
    for (int i = 0; i < 32; ++i) acc[i] = 0.f;
    for (int k = 0; k < 128; ++k) {
        float wv = pw[k * 256 + t];
#pragma unroll
        for (int i = 0; i < 32; ++i) acc[i] = fmaf(es[i][k], wv, acc[i]);
    }
    float b = pb[t];
#pragma unroll
    for (int i = 0; i < 32; ++i) {
        int g = g0 + i;
        if (g < B) out[(size_t)g * 256 + t] = acc[i] + b;
    }
}

// ---------------------------------------------------------------------------
extern "C" void kernel_launch(void* const* d_in, const int* in_sizes, int n_in,
                              void* d_out, int out_size, void* d_ws, size_t ws_size,
                              hipStream_t stream) {
    const float* x = (const float*)d_in[0];
    const int* ei = (const int*)d_in[1];
    const int* batch = (const int*)d_in[2];
    const float* W0 = (const float*)d_in[3];
    const float* b0 = (const float*)d_in[4];
    const float* W1 = (const float*)d_in[5];
    const float* b1 = (const float*)d_in[6];
    const float* W2 = (const float*)d_in[7];
    const float* b2 = (const float*)d_in[8];
    const float* gw = (const float*)d_in[9];
    const float* gb = (const float*)d_in[10];
    const float* pw = (const float*)d_in[11];
    const float* pb = (const float*)d_in[12];
    float* out = (float*)d_out;

    const int N = in_sizes[2];
    const int E = in_sizes[1] / 2;
    const int B = out_size / 256;
    (void)n_in;

    const int* esrc = ei;
    const int* edst = ei + E;

    char* p = (char*)d_ws;
    auto carve = [&](size_t bytes) {
        char* r = p;
        p += (bytes + 255) & ~(size_t)255;
        return r;
    };
    unsigned int* xd = (unsigned int*)carve((size_t)N * 48 * 4);
    unsigned int* hA = (unsigned int*)carve((size_t)N * 64 * 4);
    unsigned int* hB = (unsigned int*)carve((size_t)N * 64 * 4);
    float* emb = (float*)carve((size_t)B * 128 * 4);
    int* csr_src = (int*)carve((size_t)E * 4);
    float* dis = (float*)carve((size_t)N * 4);
    int* cnt = (int*)carve((size_t)N * 4);
    int* rowstart = (int*)carve((size_t)(N + 1) * 4);
    int* cursor = (int*)carve((size_t)N * 4);
    float* gate = (float*)carve((size_t)N * 4);
    int* goff = (int*)carve((size_t)(B + 1) * 4);
    int* bsum = (int*)carve((size_t)4096 * 4);
    unsigned short* wp0 = (unsigned short*)carve((size_t)3 * 512 * 8 * 2);
    unsigned short* wp1 = (unsigned short*)carve((size_t)4 * 512 * 8 * 2);
    unsigned short* wp2 = (unsigned short*)carve((size_t)4 * 512 * 8 * 2);
    if ((size_t)(p - (char*)d_ws) > ws_size) return;

    const int nb = (N + 2047) / 2048;

    hipMemsetAsync(cnt, 0, (size_t)N * 4, stream);
    k_count<<<(E + 255) / 256, 256, 0, stream>>>(edst, cnt, E);
    k_dis<<<(N + 255) / 256, 256, 0, stream>>>(cnt, dis, N);
    k_scan1<<<nb, 256, 0, stream>>>(cnt, rowstart + 1, bsum, N);
    k_scan2<<<1, 256, 0, stream>>>(bsum, nb);
    k_scan3<<<nb, 256, 0, stream>>>(rowstart, bsum, N);
    hipMemcpyAsync(cursor, rowstart, (size_t)N * 4, hipMemcpyDeviceToDevice, stream);
    k_fill<<<(E + 255) / 256, 256, 0, stream>>>(esrc, edst, cursor, csr_src, E);

    k_cvtw<<<6, 256, 0, stream>>>(W0, wp0, 82, 3);
    k_cvtw<<<8, 256, 0, stream>>>(W1, wp1, 128, 4);
    k_cvtw<<<8, 256, 0, stream>>>(W2, wp2, 128, 4);

    // xd = bf16(dis * x), padded to 96 cols
    k_xd<<<(N * 48 + 255) / 256, 256, 0, stream>>>(x, dis, xd, N);

    const int fb = (N + 63) / 64;

    // layer 0: xd -> hA (bf16, dis-prescaled)
    k_fused<3, true, false><<<fb, 256, 0, stream>>>(
        xd, dis, rowstart, csr_src, wp0, b0, (unsigned short*)hA,
        nullptr, nullptr, nullptr, N);
    // layer 1: hA -> hB (bf16, dis-prescaled)
    k_fused<4, true, false><<<fb, 256, 0, stream>>>(
        hA, dis, rowstart, csr_src, wp1, b1, (unsigned short*)hB,
        nullptr, nullptr, nullptr, N);
    // layer 2: hB -> hA (unscaled) + gate
    k_fused<4, false, true><<<fb, 256, 0, stream>>>(
        hB, dis, rowstart, csr_src, wp2, b2, (unsigned short*)hA,
        gw, gb, gate, N);

    // pooling + projection
    k_bounds<<<(B + 1 + 255) / 256, 256, 0, stream>>>(batch, goff, N, B);
    k_pool<<<(B + 3) / 4, 256, 0, stream>>>((const unsigned short*)hA, gate, goff, emb, B);
    k_proj<<<(B + 31) / 32, 256, 0, stream>>>(emb, pw, pb, out, B);
}